// Round 8
// baseline (133.607 us; speedup 1.0000x reference)
//
#include <hip/hip_runtime.h>
#include <hip/hip_bf16.h>

#define N 1024
#define F 32
#define H 64
#define EA 8

typedef __attribute__((ext_vector_type(8))) short bf16x8;    // 8 bf16 in 4 VGPRs
typedef __attribute__((ext_vector_type(16))) float f32x16;   // MFMA C/D

union FragAB { bf16x8 v; unsigned u[4]; };

typedef const __attribute__((address_space(1))) void global_cv;
typedef __attribute__((address_space(3))) void lds_v;

// async global->LDS: 64 lanes x 16B contiguous, dest = wave-uniform base + lane*16
__device__ __forceinline__ void stage_1kb(const float* g, float* l, int lane) {
    __builtin_amdgcn_global_load_lds((global_cv*)(g + lane * 4), (lds_v*)l, 16, 0, 0);
}

// pack two f32 -> one u32 (bf16(a) lo, bf16(b) hi), RNE
__device__ __forceinline__ unsigned pk(float a, float b) {
    union { __hip_bfloat162 h; unsigned u; } c;
    c.h = __float22bfloat162_rn(float2{a, b});
    return c.u;
}

// Kernel 1: sv[v,h] = b[h] + sum_f X[v,f]*(W[f,h]-W[32+f,h]); nb[v,h] = sum_f X[v,f]*W[32+f,h]
// Also zeroes out[]. One wave per v; lane = h.
__global__ __launch_bounds__(256) void precompute_terms(
    const float* __restrict__ X, const float* __restrict__ W, const float* __restrict__ b,
    float* __restrict__ sv, float* __restrict__ nb, float* __restrict__ out)
{
    const int lane = threadIdx.x & 63;
    const int wid  = threadIdx.x >> 6;
    const int v    = blockIdx.x * 4 + wid;

    float4 xr[8];
    const float4* xp = (const float4*)(X + (size_t)v * F);
#pragma unroll
    for (int i = 0; i < 8; ++i) xr[i] = xp[i];
    const float* xf = (const float*)xr;

    float s = b[lane];
    float n = 0.f;
#pragma unroll
    for (int f = 0; f < F; ++f) {
        float ws = W[f * H + lane];
        float wd = W[(F + f) * H + lane];
        s = fmaf(xf[f], ws - wd, s);
        n = fmaf(xf[f], wd, n);
    }
    const int idx = v * H + lane;
    sv[idx]  = s;
    nb[idx]  = n;
    out[idx] = 0.f;
}

// Kernel 2: MFMA 32x32x16 bf16.
//   k=0..7 : E[v,w,e] x We[e,h];  k=8: 1.0 x sv[v,h];  k=9: (mask?0:-1) x 1e30
//   C-init = nb[w,h] in C-layout (v-invariant -> loaded once).
// All 8 vi E-tiles async-DMA'd to wave-private LDS up front (8 x 1KB), A/sv
// preloaded to VGPRs, ONE s_waitcnt -> loop body is LDS+MFMA only (no global
// loads, no barriers). Results via direct device atomics (fan-in 32 w-tiles).
// Grid: 128 v-chunks x 8 w-quads = 1024 blocks, 4 waves; LDS 32KB/block.
__global__ __launch_bounds__(256, 4) void edge_mfma(
    const int* __restrict__ A, const float* __restrict__ Edge, const float* __restrict__ W,
    const float* __restrict__ sv, const float* __restrict__ nb, float* __restrict__ out)
{
    const int lane = threadIdx.x & 63;
    const int wid  = threadIdx.x >> 6;
    const int lg   = lane >> 5;          // k-octet group (0: k=0-7, 1: k=8-15)
    const int ln   = lane & 31;          // A-row / B,C-col index
    const int wq   = blockIdx.x & 7;
    const int vch  = blockIdx.x >> 3;
    const int wbase = wq * 128 + wid * 32;
    const int vbase = vch * 8;

    __shared__ float ebuf[4][8][256];    // [wid][vi][32 rows x 8 attrs] = 32 KB

    // 1) async-stage all 8 vi E-tiles (1KB DMA each, wave-private dest)
    const float* eg = Edge + ((size_t)vbase * N + wbase) * EA;
#pragma unroll
    for (int vi = 0; vi < 8; ++vi)
        stage_1kb(eg + (size_t)vi * N * EA, &ebuf[wid][vi][0], lane);

    // 2) preload A-masks and sv for all vi (flies with the DMAs)
    int am[8]; float s0v[8], s1v[8];
#pragma unroll
    for (int vi = 0; vi < 8; ++vi) {
        am[vi]  = A[(size_t)(vbase + vi) * N + wbase + ln];
        s0v[vi] = sv[(size_t)(vbase + vi) * H + ln];
        s1v[vi] = sv[(size_t)(vbase + vi) * H + 32 + ln];
    }

    // 3) B static: We[e][h] packed in k-octet 0; zeros in k-octet 1
    FragAB bfr[2];
#pragma unroll
    for (int half = 0; half < 2; ++half) {
        const int n = half * 32 + ln;
#pragma unroll
        for (int q = 0; q < 4; ++q) {
            unsigned we = pk(W[(2 * F + 2 * q) * H + n], W[(2 * F + 2 * q + 1) * H + n]);
            bfr[half].u[q] = (lg == 0) ? we : 0u;
        }
    }

    // 4) C-init = nb in MFMA C-layout (v-invariant): row=(r&3)+8*(r>>2)+4*lg
    f32x16 cnb[2];
#pragma unroll
    for (int half = 0; half < 2; ++half)
#pragma unroll
        for (int r = 0; r < 16; ++r) {
            const int row = (r & 3) + 8 * (r >> 2) + 4 * lg;
            cnb[half][r] = nb[(size_t)(wbase + row) * H + half * 32 + ln];
        }

    __builtin_amdgcn_s_waitcnt(0);       // drain DMAs + preloads (once per wave)
    __builtin_amdgcn_sched_barrier(0);

    // 5) memory-free MFMA loop
#pragma unroll
    for (int vi = 0; vi < 8; ++vi) {
        const float* eL = &ebuf[wid][vi][0];
        const float4 ca = *(const float4*)&eL[ln * 8];       // ds_read_b128
        const float4 cb = *(const float4*)&eL[ln * 8 + 4];   // (lanes>=32 mirror: free)

        FragAB afr;
        const unsigned mpat = am[vi] ? 0x00003f80u : 0xbf803f80u;  // k8=1.0, k9=0/-1
        afr.u[0] = (lg == 0) ? pk(ca.x, ca.y) : mpat;
        afr.u[1] = (lg == 0) ? pk(ca.z, ca.w) : 0u;
        afr.u[2] = (lg == 0) ? pk(cb.x, cb.y) : 0u;
        afr.u[3] = (lg == 0) ? pk(cb.z, cb.w) : 0u;

        FragAB b0 = bfr[0], b1 = bfr[1];
        if (lg) { b0.u[0] = pk(s0v[vi], 1e30f); b1.u[0] = pk(s1v[vi], 1e30f); }

        const f32x16 d0 = __builtin_amdgcn_mfma_f32_32x32x16_bf16(afr.v, b0.v, cnb[0], 0, 0, 0);
        const f32x16 d1 = __builtin_amdgcn_mfma_f32_32x32x16_bf16(afr.v, b1.v, cnb[1], 0, 0, 0);

        float p0 = 0.f, p1 = 0.f;
#pragma unroll
        for (int r = 0; r < 16; ++r) {
            p0 += fmaxf(d0[r], 0.f);
            p1 += fmaxf(d1[r], 0.f);
        }
        // lanes L and L+32 hold complementary row-halves of the same column:
        // both atomically add to the same address (2-way, L2-serialized, cheap)
        unsafeAtomicAdd(&out[(size_t)(vbase + vi) * H + ln], p0);
        unsafeAtomicAdd(&out[(size_t)(vbase + vi) * H + 32 + ln], p1);
    }
}

extern "C" void kernel_launch(void* const* d_in, const int* in_sizes, int n_in,
                              void* d_out, int out_size, void* d_ws, size_t ws_size,
                              hipStream_t stream) {
    const int*   A    = (const int*)d_in[0];
    const float* X    = (const float*)d_in[1];
    const float* Edge = (const float*)d_in[2];
    const float* W    = (const float*)d_in[3];
    const float* b    = (const float*)d_in[4];
    float* out = (float*)d_out;

    float* sv = (float*)d_ws;
    float* nb = sv + N * H;

    precompute_terms<<<dim3(256), dim3(256), 0, stream>>>(X, W, b, sv, nb, out);
    edge_mfma<<<dim3(1024), dim3(256), 0, stream>>>(A, Edge, W, sv, nb, out);
}

// Round 9
// 89.295 us; speedup vs baseline: 1.4962x; 1.4962x over previous
//
#include <hip/hip_runtime.h>
#include <hip/hip_bf16.h>

#define N 1024
#define F 32
#define H 64
#define EA 8

typedef __attribute__((ext_vector_type(8))) short bf16x8;    // 8 bf16 in 4 VGPRs
typedef __attribute__((ext_vector_type(16))) float f32x16;   // MFMA C/D

union FragAB { bf16x8 v; unsigned u[4]; };

// pack two f32 -> one u32 (bf16(a) lo, bf16(b) hi), RNE
__device__ __forceinline__ unsigned pk(float a, float b) {
    union { __hip_bfloat162 h; unsigned u; } c;
    c.h = __float22bfloat162_rn(float2{a, b});
    return c.u;
}

// Kernel 1: sv[v,h] = b[h] + sum_f X[v,f]*(W[f,h]-W[32+f,h]); nb[v,h] = sum_f X[v,f]*W[32+f,h]
// Also zeroes out[]. One wave per v; lane = h.
__global__ __launch_bounds__(256) void precompute_terms(
    const float* __restrict__ X, const float* __restrict__ W, const float* __restrict__ b,
    float* __restrict__ sv, float* __restrict__ nb, float* __restrict__ out)
{
    const int lane = threadIdx.x & 63;
    const int wid  = threadIdx.x >> 6;
    const int v    = blockIdx.x * 4 + wid;

    float4 xr[8];
    const float4* xp = (const float4*)(X + (size_t)v * F);
#pragma unroll
    for (int i = 0; i < 8; ++i) xr[i] = xp[i];
    const float* xf = (const float*)xr;

    float s = b[lane];
    float n = 0.f;
#pragma unroll
    for (int f = 0; f < F; ++f) {
        float ws = W[f * H + lane];
        float wd = W[(F + f) * H + lane];
        s = fmaf(xf[f], ws - wd, s);
        n = fmaf(xf[f], wd, n);
    }
    const int idx = v * H + lane;
    sv[idx]  = s;
    nb[idx]  = n;
    out[idx] = 0.f;
}

// Kernel 2: MFMA 32x32x16 bf16 (R7 structure + batched preloads + depth-2 E prefetch).
//   k=0..7 : E[v,w,e] x We[e,h];  k=8: 1.0 x sv[v,h];  k=9: (mask?0:-1) x 1e30
//   C-init = nb[w,h] in C-layout (v-invariant). Wave = 32-w tile x 64 h, loops 8 v.
// E lives in registers (global_load_dwordx4, compiler-scheduled vmcnt); A/sv for
// all 8 vi batched up front (their latency hides under W/nb setup). No explicit
// waitcnt/sched_barrier. Partials via conflict-free ds_write, block reduce,
// fan-in-8 device atomics.
__global__ __launch_bounds__(256, 4) void edge_mfma(
    const int* __restrict__ A, const float* __restrict__ Edge, const float* __restrict__ W,
    const float* __restrict__ sv, const float* __restrict__ nb, float* __restrict__ out)
{
    const int lane = threadIdx.x & 63;
    const int wid  = threadIdx.x >> 6;
    const int lg   = lane >> 5;          // k-octet group (0: k=0-7, 1: k=8-15)
    const int ln   = lane & 31;          // A-row / B,C-col index
    const int wq   = blockIdx.x & 7;
    const int vch  = blockIdx.x >> 3;
    const int wbase = wq * 128 + wid * 32;
    const int vbase = vch * 8;

    __shared__ float part[4][2][8][64];  // [wid][lg][vi][col] = 16 KB

    // --- batched preloads: A-mask + sv for all 8 vi (latency hidden by setup) ---
    const int* ap = A + (size_t)vbase * N + wbase + ln;
    int am[8]; float s0v[8], s1v[8];
#pragma unroll
    for (int vi = 0; vi < 8; ++vi) {
        am[vi]  = ap[(size_t)vi * N];
        s0v[vi] = sv[(size_t)(vbase + vi) * H + ln];
        s1v[vi] = sv[(size_t)(vbase + vi) * H + 32 + ln];
    }

    // E row pointer for this lane's w (=wbase+ln); v-stride = N*EA/4 = 2048 float4
    const float4* ep = (const float4*)(Edge + ((size_t)vbase * N + wbase + ln) * EA);
    // depth-2 register prefetch ring
    float4 eA[2], eB[2];
    eA[0] = ep[0];    eB[0] = ep[1];
    eA[1] = ep[2048]; eB[1] = ep[2049];

    // B static: We[e][h] packed in k-octet 0; zeros in k-octet 1
    FragAB bfr[2];
#pragma unroll
    for (int half = 0; half < 2; ++half) {
        const int n = half * 32 + ln;
#pragma unroll
        for (int q = 0; q < 4; ++q) {
            unsigned we = pk(W[(2 * F + 2 * q) * H + n], W[(2 * F + 2 * q + 1) * H + n]);
            bfr[half].u[q] = (lg == 0) ? we : 0u;
        }
    }

    // C-init = nb in MFMA C-layout: row=(r&3)+8*(r>>2)+4*lg, col=ln(+32*half)
    f32x16 cnb[2];
#pragma unroll
    for (int half = 0; half < 2; ++half)
#pragma unroll
        for (int r = 0; r < 16; ++r) {
            const int row = (r & 3) + 8 * (r >> 2) + 4 * lg;
            cnb[half][r] = nb[(size_t)(wbase + row) * H + half * 32 + ln];
        }

#pragma unroll
    for (int vi = 0; vi < 8; ++vi) {
        const float4 ca = eA[vi & 1];
        const float4 cb = eB[vi & 1];
        if (vi < 6) {
            eA[vi & 1] = ep[(vi + 2) * 2048];
            eB[vi & 1] = ep[(vi + 2) * 2048 + 1];
        }

        FragAB afr;
        const unsigned mpat = am[vi] ? 0x00003f80u : 0xbf803f80u;  // k8=1.0, k9=0/-1
        afr.u[0] = (lg == 0) ? pk(ca.x, ca.y) : mpat;
        afr.u[1] = (lg == 0) ? pk(ca.z, ca.w) : 0u;
        afr.u[2] = (lg == 0) ? pk(cb.x, cb.y) : 0u;
        afr.u[3] = (lg == 0) ? pk(cb.z, cb.w) : 0u;

        FragAB b0 = bfr[0], b1 = bfr[1];
        if (lg) { b0.u[0] = pk(s0v[vi], 1e30f); b1.u[0] = pk(s1v[vi], 1e30f); }

        const f32x16 d0 = __builtin_amdgcn_mfma_f32_32x32x16_bf16(afr.v, b0.v, cnb[0], 0, 0, 0);
        const f32x16 d1 = __builtin_amdgcn_mfma_f32_32x32x16_bf16(afr.v, b1.v, cnb[1], 0, 0, 0);

        float p0 = 0.f, p1 = 0.f;
#pragma unroll
        for (int r = 0; r < 16; ++r) {
            p0 += fmaxf(d0[r], 0.f);
            p1 += fmaxf(d1[r], 0.f);
        }
        part[wid][lg][vi][ln]      = p0;   // lanes L and L+32 same bank: 2-way, free
        part[wid][lg][vi][32 + ln] = p1;
    }

    __syncthreads();
#pragma unroll
    for (int i = threadIdx.x; i < 512; i += 256) {
        const int vi = i >> 6, h = i & 63;
        float s = 0.f;
#pragma unroll
        for (int w4 = 0; w4 < 4; ++w4)
#pragma unroll
            for (int g = 0; g < 2; ++g) s += part[w4][g][vi][h];
        unsafeAtomicAdd(&out[(size_t)(vbase + vi) * H + h], s);
    }
}

extern "C" void kernel_launch(void* const* d_in, const int* in_sizes, int n_in,
                              void* d_out, int out_size, void* d_ws, size_t ws_size,
                              hipStream_t stream) {
    const int*   A    = (const int*)d_in[0];
    const float* X    = (const float*)d_in[1];
    const float* Edge = (const float*)d_in[2];
    const float* W    = (const float*)d_in[3];
    const float* b    = (const float*)d_in[4];
    float* out = (float*)d_out;

    float* sv = (float*)d_ws;
    float* nb = sv + N * H;

    precompute_terms<<<dim3(256), dim3(256), 0, stream>>>(X, W, b, sv, nb, out);
    edge_mfma<<<dim3(1024), dim3(256), 0, stream>>>(A, Edge, W, sv, nb, out);
}